// Round 1
// baseline (668.228 us; speedup 1.0000x reference)
//
#include <hip/hip_runtime.h>

typedef __bf16 bf16x8 __attribute__((ext_vector_type(8)));
typedef __bf16 bf16x4 __attribute__((ext_vector_type(4)));
typedef float  f32x4  __attribute__((ext_vector_type(4)));

#define HW   256
#define HW2  65536

// 2048 blocks: (b,o) pair = blk>>1, h-tile = blk&1 (128 rows each).
// 512 threads = 8 waves; wave w owns h rows [h0+16w, h0+16w+16).
__global__ __launch_bounds__(512, 2) void attn_kernel(
    const float* __restrict__ x1, const float* __restrict__ x2,
    const float* __restrict__ Wq, const float* __restrict__ bq,
    const float* __restrict__ Wk, const float* __restrict__ bk,
    const float* __restrict__ Wv, const float* __restrict__ bv,
    const float* __restrict__ Wa, const float* __restrict__ ba,
    float* __restrict__ out)
{
    // K staging: 64 g-rows x 256 w (stride 264 bf16 = 528B, 16B-aligned rows)
    __shared__ __align__(16) __bf16 sKV[64 * 264];
    // V transposed: 256 w-rows x 64 g (stride 72 bf16 = 144B, 16B-aligned rows)
    __shared__ __align__(16) __bf16 sVT[256 * 72];
    // P (unnormalized exp), 128 h-rows x 256 g, bf16
    __shared__ __align__(16) __bf16 sP[128 * 264];
    __shared__ float sRow[128];

    const int tid  = threadIdx.x;
    const int wid  = tid >> 6;      // wave 0..7
    const int lane = tid & 63;
    const int quad = lane >> 4;     // 0..3
    const int c    = lane & 15;     // 0..15

    const int blk  = blockIdx.x;
    const int pair = blk >> 1;      // b*32 + o
    const int ht   = blk & 1;
    const int b    = pair >> 5;
    const int o    = pair & 31;
    const int h0   = ht * 128;

    const float wq0 = Wq[o*3+0], wq1 = Wq[o*3+1], wq2 = Wq[o*3+2], bqv = bq[o];
    const float wk0 = Wk[o*3+0], wk1 = Wk[o*3+1], wk2 = Wk[o*3+2], bkv = bk[o];
    const float wv0 = Wv[o*3+0], wv1 = Wv[o*3+1], wv2 = Wv[o*3+2], bvv = bv[o];
    const float wa0 = Wa[o*3+0], wa1 = Wa[o*3+1], wa2 = Wa[o*3+2], bav = ba[o];
    const float inv = 1.0f / 256.0f;

    const float* x1b = x1 + b * 3 * HW2;
    const float* x2b = x2 + b * 3 * HW2;

    // ---------- Q fragments (A-operand), pre-scaled by inv_scale ----------
    // A[m=lane&15][k=quad*8+j]; m -> h row, k -> w
    bf16x8 qf[8];
    {
        const int hq = h0 + 16*wid + c;
        const float* r0 = x1b + 0*HW2 + hq*HW;
        const float* r1 = x1b + 1*HW2 + hq*HW;
        const float* r2 = x1b + 2*HW2 + hq*HW;
#pragma unroll
        for (int kt = 0; kt < 8; ++kt) {
            const int wc = 32*kt + 8*quad;
            float4 a0 = *(const float4*)(r0 + wc), a1 = *(const float4*)(r0 + wc + 4);
            float4 b0 = *(const float4*)(r1 + wc), b1 = *(const float4*)(r1 + wc + 4);
            float4 c0 = *(const float4*)(r2 + wc), c1 = *(const float4*)(r2 + wc + 4);
            bf16x8 q;
            q[0] = (__bf16)((wq0*a0.x + wq1*b0.x + wq2*c0.x + bqv) * inv);
            q[1] = (__bf16)((wq0*a0.y + wq1*b0.y + wq2*c0.y + bqv) * inv);
            q[2] = (__bf16)((wq0*a0.z + wq1*b0.z + wq2*c0.z + bqv) * inv);
            q[3] = (__bf16)((wq0*a0.w + wq1*b0.w + wq2*c0.w + bqv) * inv);
            q[4] = (__bf16)((wq0*a1.x + wq1*b1.x + wq2*c1.x + bqv) * inv);
            q[5] = (__bf16)((wq0*a1.y + wq1*b1.y + wq2*c1.y + bqv) * inv);
            q[6] = (__bf16)((wq0*a1.z + wq1*b1.z + wq2*c1.z + bqv) * inv);
            q[7] = (__bf16)((wq0*a1.w + wq1*b1.w + wq2*c1.w + bqv) * inv);
            qf[kt] = q;
        }
    }

    // ---------- S = (Q/256)K^T + A, accumulated in registers ----------
    // acc[ai] tile: rows h0+16wid+4q+r, cols 16*ai + c
    f32x4 acc[16];
#pragma unroll
    for (int g0i = 0; g0i < 4; ++g0i) {
        const int g0 = g0i * 64;
        __syncthreads();
        // stage K rows g0..g0+63 (row-major, w contiguous)
#pragma unroll
        for (int i = 0; i < 8; ++i) {
            const int s   = i*512 + tid;        // 0..4095
            const int row = s >> 6;
            const int c4  = (s & 63) * 4;
            const int g   = g0 + row;
            float4 u0 = *(const float4*)(x2b + 0*HW2 + g*HW + c4);
            float4 u1 = *(const float4*)(x2b + 1*HW2 + g*HW + c4);
            float4 u2 = *(const float4*)(x2b + 2*HW2 + g*HW + c4);
            bf16x4 kv;
            kv[0] = (__bf16)(wk0*u0.x + wk1*u1.x + wk2*u2.x + bkv);
            kv[1] = (__bf16)(wk0*u0.y + wk1*u1.y + wk2*u2.y + bkv);
            kv[2] = (__bf16)(wk0*u0.z + wk1*u1.z + wk2*u2.z + bkv);
            kv[3] = (__bf16)(wk0*u0.w + wk1*u1.w + wk2*u2.w + bkv);
            *(bf16x4*)(&sKV[row*264 + c4]) = kv;
        }
        __syncthreads();
#pragma unroll
        for (int ag = 0; ag < 4; ++ag) {
            const int ai   = g0i*4 + ag;
            const int gcol = g0 + 16*ag + c;
            // init accumulator with A (fp32-exact bias/score offset)
            f32x4 a;
#pragma unroll
            for (int r = 0; r < 4; ++r) {
                const int hh = h0 + 16*wid + 4*quad + r;
                a[r] = wa0 * x2b[0*HW2 + hh*HW + gcol]
                     + wa1 * x2b[1*HW2 + hh*HW + gcol]
                     + wa2 * x2b[2*HW2 + hh*HW + gcol] + bav;
            }
#pragma unroll
            for (int kt = 0; kt < 8; ++kt) {
                bf16x8 bf = *(const bf16x8*)(&sKV[(16*ag + c)*264 + 32*kt + 8*quad]);
                a = __builtin_amdgcn_mfma_f32_16x16x32_bf16(qf[kt], bf, a, 0, 0, 0);
            }
            acc[ai] = a;
        }
    }

    // ---------- in-register softmax over g (row = 4*quad + r within wave) ----------
    float lrow[4];
#pragma unroll
    for (int r = 0; r < 4; ++r) {
        float m = acc[0][r];
#pragma unroll
        for (int t = 1; t < 16; ++t) m = fmaxf(m, acc[t][r]);
#pragma unroll
        for (int d = 8; d >= 1; d >>= 1) m = fmaxf(m, __shfl_xor(m, d, 64));
        float l = 0.0f;
#pragma unroll
        for (int t = 0; t < 16; ++t) {
            float e = __expf(acc[t][r] - m);
            acc[t][r] = e;
            l += e;
        }
#pragma unroll
        for (int d = 8; d >= 1; d >>= 1) l += __shfl_xor(l, d, 64);
        lrow[r] = l;
    }
    if (c == 0) {
#pragma unroll
        for (int r = 0; r < 4; ++r) sRow[16*wid + 4*quad + r] = lrow[r];
    }
    // write unnormalized P (bf16) — only this wave reads its own rows back
#pragma unroll
    for (int t = 0; t < 16; ++t) {
#pragma unroll
        for (int r = 0; r < 4; ++r) {
            sP[(16*wid + 4*quad + r)*264 + 16*t + c] = (__bf16)acc[t][r];
        }
    }

    // ---------- O^T = V^T P^T  (both operands contiguous in LDS) ----------
    f32x4 oacc[16];
#pragma unroll
    for (int t = 0; t < 16; ++t) oacc[t] = (f32x4){0.f, 0.f, 0.f, 0.f};

    for (int g0i = 0; g0i < 4; ++g0i) {
        const int g0 = g0i * 64;
        __syncthreads();
        // stage V transposed: sVT[w][gl], coalesced x2 loads (lane -> w)
        {
            const int w  = tid & 255;
            const int gs = (tid >> 8) * 32;
#pragma unroll
            for (int i = 0; i < 8; ++i) {
                const int gl = gs + i*4;
                const int g  = g0 + gl;
                bf16x4 pk;
#pragma unroll
                for (int j = 0; j < 4; ++j) {
                    float u0 = x2b[0*HW2 + (g+j)*HW + w];
                    float u1 = x2b[1*HW2 + (g+j)*HW + w];
                    float u2 = x2b[2*HW2 + (g+j)*HW + w];
                    pk[j] = (__bf16)(wv0*u0 + wv1*u1 + wv2*u2 + bvv);
                }
                *(bf16x4*)(&sVT[w*72 + gl]) = pk;
            }
        }
        __syncthreads();
        // B-frags (P^T): independent of wt — hoist
        bf16x8 pf0 = *(const bf16x8*)(&sP[(16*wid + c)*264 + g0 +  0 + 8*quad]);
        bf16x8 pf1 = *(const bf16x8*)(&sP[(16*wid + c)*264 + g0 + 32 + 8*quad]);
#pragma unroll
        for (int wt = 0; wt < 16; ++wt) {
            bf16x8 vf0 = *(const bf16x8*)(&sVT[(16*wt + c)*72 +  0 + 8*quad]);
            oacc[wt] = __builtin_amdgcn_mfma_f32_16x16x32_bf16(vf0, pf0, oacc[wt], 0, 0, 0);
            bf16x8 vf1 = *(const bf16x8*)(&sVT[(16*wt + c)*72 + 32 + 8*quad]);
            oacc[wt] = __builtin_amdgcn_mfma_f32_16x16x32_bf16(vf1, pf1, oacc[wt], 0, 0, 0);
        }
    }

    // ---------- epilogue: normalize by row-sum, fp32 stores ----------
    // oacc[wt] element r: O^T[w = 16wt+4q+r][h = 16wid+c]
    const float rinv = 1.0f / sRow[16*wid + c];
    float* outp = out + (size_t)pair * HW2 + (size_t)(h0 + 16*wid + c) * HW;
#pragma unroll
    for (int wt = 0; wt < 16; ++wt) {
#pragma unroll
        for (int r = 0; r < 4; ++r) {
            outp[16*wt + 4*quad + r] = oacc[wt][r] * rinv;
        }
    }
}

extern "C" void kernel_launch(void* const* d_in, const int* in_sizes, int n_in,
                              void* d_out, int out_size, void* d_ws, size_t ws_size,
                              hipStream_t stream) {
    const float* x1 = (const float*)d_in[0];
    const float* x2 = (const float*)d_in[1];
    const float* Wq = (const float*)d_in[2];
    const float* bq = (const float*)d_in[3];
    const float* Wk = (const float*)d_in[4];
    const float* bk = (const float*)d_in[5];
    const float* Wv = (const float*)d_in[6];
    const float* bv = (const float*)d_in[7];
    const float* Wa = (const float*)d_in[8];
    const float* ba = (const float*)d_in[9];
    float* out = (float*)d_out;

    attn_kernel<<<dim3(2048), dim3(512), 0, stream>>>(
        x1, x2, Wq, bq, Wk, bk, Wv, bv, Wa, ba, out);
}